// Round 1
// baseline (572.826 us; speedup 1.0000x reference)
//
#include <hip/hip_runtime.h>

// Soft-circuit FP32 scale-by-2^k, reduced to integer bit ops.
// Row layout (element e <-> bit e of packed word):
//   bit 0      = sign
//   bits 1..8  = exponent, element 1 = MSB (big-endian in element order)
//   bits 9..31 = mantissa, element 9 = MSB
//
// Per row (k word = kw, x word = xw):
//   ek   = int(exponent bits of k)          (8-bit)
//   val  = 0x80 | top7 mantissa bits of k   (8-bit significand)
//   s    = (ek - 127) & 7
//   kabs = val >> (7 - s)                   (8-bit)
//   kfin = sign_k ? (-kabs) & 0xFF : kabs
//   enew = (ex + kfin) & 0xFF
//   res  = (kw & ~1)==0 ? xw : sign_x | enew(BE in bits 1..8) | mant_x
//
// Memory-bound: 768 MB total traffic -> ~122 us floor @6.3 TB/s.

__device__ __forceinline__ unsigned rev8(unsigned v) {
    // reverse the low 8 bits
    return __builtin_bitreverse32(v) >> 24;
}

__global__ __launch_bounds__(256) void spike_scale_kernel(
        const float4* __restrict__ x4,
        const float4* __restrict__ k4,
        float4* __restrict__ o4,
        int nvec) {
    int idx = blockIdx.x * 256 + threadIdx.x;
    if (idx >= nvec) return;

    float4 vx = x4[idx];
    float4 vk = k4[idx];

    unsigned g    = (unsigned)(idx & 7);   // position of this thread's 4 elems in the row
    unsigned base = g * 4u;

    unsigned nibx = (unsigned)(vx.x != 0.0f)
                  | ((unsigned)(vx.y != 0.0f) << 1)
                  | ((unsigned)(vx.z != 0.0f) << 2)
                  | ((unsigned)(vx.w != 0.0f) << 3);
    unsigned nibk = (unsigned)(vk.x != 0.0f)
                  | ((unsigned)(vk.y != 0.0f) << 1)
                  | ((unsigned)(vk.z != 0.0f) << 2)
                  | ((unsigned)(vk.w != 0.0f) << 3);

    // pack x word in low 32, k word in high 32; OR-reduce across the 8-lane group
    unsigned long long w = ((unsigned long long)nibx << base)
                         | ((unsigned long long)nibk << (32u + base));
    w |= __shfl_xor(w, 1);
    w |= __shfl_xor(w, 2);
    w |= __shfl_xor(w, 4);

    unsigned xw = (unsigned)w;
    unsigned kw = (unsigned)(w >> 32);

    // decode k
    unsigned ek   = rev8((kw >> 1) & 0xFFu);                       // exponent of k as int
    unsigned val  = 0x80u | (__builtin_bitreverse32((kw >> 9) & 0x7Fu) >> 25); // 1.m (8-bit)
    unsigned s    = (ek - 127u) & 7u;
    unsigned kabs = val >> (7u - s);
    unsigned kfin = (kw & 1u) ? ((0u - kabs) & 0xFFu) : kabs;

    // new exponent for x
    unsigned ex   = rev8((xw >> 1) & 0xFFu);
    unsigned enew = (ex + kfin) & 0xFFu;

    unsigned scaled = (xw & 1u) | (rev8(enew) << 1) | (xw & 0xFFFFFE00u);
    unsigned res    = ((kw & ~1u) == 0u) ? xw : scaled;

    float4 out;
    out.x = (float)((res >> (base + 0u)) & 1u);
    out.y = (float)((res >> (base + 1u)) & 1u);
    out.z = (float)((res >> (base + 2u)) & 1u);
    out.w = (float)((res >> (base + 3u)) & 1u);
    o4[idx] = out;
}

extern "C" void kernel_launch(void* const* d_in, const int* in_sizes, int n_in,
                              void* d_out, int out_size, void* d_ws, size_t ws_size,
                              hipStream_t stream) {
    const float4* x4 = (const float4*)d_in[0];
    const float4* k4 = (const float4*)d_in[1];
    float4* o4 = (float4*)d_out;

    int n_elems = in_sizes[0];          // N * 32
    int nvec    = n_elems / 4;          // float4 vectors
    int blocks  = (nvec + 255) / 256;

    spike_scale_kernel<<<blocks, 256, 0, stream>>>(x4, k4, o4, nvec);
}